// Round 1
// baseline (309.745 us; speedup 1.0000x reference)
//
#include <hip/hip_runtime.h>
#include <hip/hip_bf16.h>
#include <stdint.h>

// ---------------------------------------------------------------------------
// MHA forward, bf16 MFMA pipeline.
//   x[4,2048,1024] fp32; Wq/Wk/Wv/Wo [1024,1024] fp32; biases fp32.
//   out [4,2048,1024] fp32.
// ws layout (bytes):
//   [0,16M)   xb   : x as bf16 [8192][1024]
//   [16M,24M) wt   : Wq^T,Wk^T,Wv^T,Wo^T bf16, each [1024][1024] (row=out,col=in)
//   [24M,40M) Qbh  : [64][2048][64] bf16 (scaled by 0.125*log2e)
//   [40M,56M) Kbh  : [64][2048][64] bf16
//   [56M,72M) Vbh  : [64][2048][64] bf16
//   [72M,88M) ctx  : [8192][1024] bf16
// ---------------------------------------------------------------------------

typedef __bf16 bf16;
typedef __bf16 bf16x8 __attribute__((ext_vector_type(8)));
typedef float  f32x4  __attribute__((ext_vector_type(4)));

#define XB_OFF   (0ull)
#define WT_OFF   (16ull << 20)
#define Q_OFF    (24ull << 20)
#define K_OFF    (40ull << 20)
#define V_OFF    (56ull << 20)
#define CTX_OFF  (72ull << 20)

// 1/sqrt(64) * log2(e), folded into Q so softmax uses exp2 directly.
#define QSCALE 0.18033688011112042591f

__device__ __forceinline__ void gload_lds16(const void* g, void* l) {
  __builtin_amdgcn_global_load_lds(
      (const __attribute__((address_space(1))) void*)g,
      (__attribute__((address_space(3))) void*)l, 16, 0, 0);
}

// --------------------------- fp32 -> bf16 x --------------------------------
__global__ __launch_bounds__(256) void cvt_x(const float* __restrict__ x,
                                             bf16* __restrict__ xb) {
  int i = blockIdx.x * 256 + threadIdx.x;          // one thread = 8 elements
  const float4* p = (const float4*)x;
  float4 a = p[(size_t)i * 2];
  float4 b = p[(size_t)i * 2 + 1];
  bf16x8 o;
  o[0] = (bf16)a.x; o[1] = (bf16)a.y; o[2] = (bf16)a.z; o[3] = (bf16)a.w;
  o[4] = (bf16)b.x; o[5] = (bf16)b.y; o[6] = (bf16)b.z; o[7] = (bf16)b.w;
  *((bf16x8*)xb + i) = o;
}

// ------------------- weight transpose + convert (W^T bf16) -----------------
__global__ __launch_bounds__(256) void cvt_w(const float* __restrict__ w0,
                                             const float* __restrict__ w1,
                                             const float* __restrict__ w2,
                                             const float* __restrict__ w3,
                                             bf16* __restrict__ wt) {
  int z = blockIdx.z;
  const float* W = (z == 0) ? w0 : (z == 1) ? w1 : (z == 2) ? w2 : w3;
  bf16* Wt = wt + (size_t)z * 1024 * 1024;
  __shared__ float tile[64][65];
  int i0 = blockIdx.y * 64, o0 = blockIdx.x * 64;
  int tid = threadIdx.x;
#pragma unroll
  for (int rep = 0; rep < 16; rep++) {
    int idx = rep * 256 + tid;
    int r = idx >> 6, c = idx & 63;
    tile[r][c] = W[(size_t)(i0 + r) * 1024 + o0 + c];
  }
  __syncthreads();
#pragma unroll
  for (int rep = 0; rep < 16; rep++) {
    int idx = rep * 256 + tid;
    int r = idx >> 6, c = idx & 63;
    Wt[(size_t)(o0 + r) * 1024 + i0 + c] = (bf16)tile[c][r];
  }
}

// --------------------------- NT bf16 GEMM ----------------------------------
// C[M,N] = A[M,1024] * Bt[N,1024]^T (+bias).  128x128 tile, BK=64, 4 waves.
// MODE 0: N=3072 fused QKV -> scatter to Qbh/Kbh/Vbh (Q scaled).
// MODE 1: N=1024 out-proj -> fp32 out.
template <int MODE>
__global__ __launch_bounds__(256, 2) void gemm_bt(
    const bf16* __restrict__ A, const bf16* __restrict__ Bt,
    const float* __restrict__ b0, const float* __restrict__ b1,
    const float* __restrict__ b2,
    bf16* __restrict__ Qo, bf16* __restrict__ Ko, bf16* __restrict__ Vo,
    float* __restrict__ out) {
  __shared__ __align__(16) bf16 a_lds[128 * 64];
  __shared__ __align__(16) bf16 b_lds[128 * 64];
  int tid = threadIdx.x;
  int lane = tid & 63, wid = tid >> 6;
  int wr = wid >> 1, wc = wid & 1;
  int g = lane >> 4, rlo = lane & 15;
  int m0 = blockIdx.x * 128, n0 = blockIdx.y * 128;

  f32x4 acc[4][4] = {};
  const char* Ab = (const char*)A;
  const char* Bb = (const char*)Bt;

  for (int k0 = 0; k0 < 1024; k0 += 64) {
    // stage A tile [128][64] and B tile [128][64]; LDS linear, global source
    // pre-swizzled by ((row&7)<<4) so frag ds_read_b128 is conflict-free.
#pragma unroll
    for (int rep = 0; rep < 4; rep++) {
      int idx = rep * 256 + tid;
      int row = idx >> 3;
      int sw = ((idx & 7) * 16) ^ ((row & 7) << 4);
      gload_lds16(Ab + ((size_t)(m0 + row) * 1024 + k0) * 2 + sw,
                  (char*)a_lds + (size_t)idx * 16);
    }
#pragma unroll
    for (int rep = 0; rep < 4; rep++) {
      int idx = rep * 256 + tid;
      int row = idx >> 3;
      int sw = ((idx & 7) * 16) ^ ((row & 7) << 4);
      gload_lds16(Bb + ((size_t)(n0 + row) * 1024 + k0) * 2 + sw,
                  (char*)b_lds + (size_t)idx * 16);
    }
    __syncthreads();
#pragma unroll
    for (int ks = 0; ks < 2; ks++) {
      bf16x8 af[4], bfr[4];
#pragma unroll
      for (int mt = 0; mt < 4; mt++) {
        int row = wr * 64 + mt * 16 + rlo;
        int koff = (ks * 32 + g * 8) ^ ((row & 7) << 3);
        af[mt] = *(const bf16x8*)&a_lds[row * 64 + koff];
      }
#pragma unroll
      for (int nt = 0; nt < 4; nt++) {
        int row = wc * 64 + nt * 16 + rlo;
        int koff = (ks * 32 + g * 8) ^ ((row & 7) << 3);
        bfr[nt] = *(const bf16x8*)&b_lds[row * 64 + koff];
      }
#pragma unroll
      for (int mt = 0; mt < 4; mt++)
#pragma unroll
        for (int nt = 0; nt < 4; nt++)
          acc[mt][nt] = __builtin_amdgcn_mfma_f32_16x16x32_bf16(
              af[mt], bfr[nt], acc[mt][nt], 0, 0, 0);
    }
    __syncthreads();
  }

  // epilogue: D layout col=lane&15, row=(lane>>4)*4+reg
#pragma unroll
  for (int nt = 0; nt < 4; nt++) {
    int n = n0 + wc * 64 + nt * 16 + rlo;
    if (MODE == 0) {
      int which = n >> 10, nn = n & 1023;
      const float* bp = (which == 0) ? b0 : (which == 1) ? b1 : b2;
      float bias = bp[nn];
      bf16* dst = (which == 0) ? Qo : (which == 1) ? Ko : Vo;
      float scale = (which == 0) ? QSCALE : 1.0f;
      int h = nn >> 6, hd = nn & 63;
#pragma unroll
      for (int mt = 0; mt < 4; mt++) {
#pragma unroll
        for (int r = 0; r < 4; r++) {
          int m = m0 + wr * 64 + mt * 16 + g * 4 + r;
          int bb = m >> 11, ss = m & 2047;
          float v = (acc[mt][nt][r] + bias) * scale;
          dst[(((size_t)(bb * 16 + h) * 2048 + ss) << 6) + hd] = (bf16)v;
        }
      }
    } else {
      float bias = b0[n];
#pragma unroll
      for (int mt = 0; mt < 4; mt++) {
#pragma unroll
        for (int r = 0; r < 4; r++) {
          int m = m0 + wr * 64 + mt * 16 + g * 4 + r;
          out[(size_t)m * 1024 + n] = acc[mt][nt][r] + bias;
        }
      }
    }
  }
}

// --------------------------- flash attention --------------------------------
// grid: (S/64, B*H). 4 waves/block, 16 q-rows per wave, KV tiles of 64.
__global__ __launch_bounds__(256, 2) void attn(const bf16* __restrict__ Q,
                                               const bf16* __restrict__ K,
                                               const bf16* __restrict__ V,
                                               bf16* __restrict__ ctx) {
  __shared__ __align__(16) bf16 k_lds[64 * 64];
  __shared__ __align__(16) bf16 v_lds[64 * 64];  // transposed: [d][t]
  __shared__ __align__(16) bf16 p_lds[64 * 64];  // per-wave 16-row slabs
  int tid = threadIdx.x, lane = tid & 63, w = tid >> 6;
  int g = lane >> 4, rlo = lane & 15;
  int bh = blockIdx.y;
  int q0 = blockIdx.x * 64;
  const bf16* Qb = Q + (size_t)bh * 2048 * 64;
  const bf16* Kb = K + (size_t)bh * 2048 * 64;
  const bf16* Vb = V + (size_t)bh * 2048 * 64;

  // Q A-frags held in registers for the whole K/V sweep.
  bf16x8 aq[2];
#pragma unroll
  for (int ks = 0; ks < 2; ks++)
    aq[ks] = *(const bf16x8*)&Qb[(size_t)(q0 + w * 16 + rlo) * 64 + ks * 32 + g * 8];

  float m_r[4], l_r[4];
  f32x4 o[4] = {};
#pragma unroll
  for (int r = 0; r < 4; r++) { m_r[r] = -1e30f; l_r[r] = 0.f; }

  for (int t0 = 0; t0 < 2048; t0 += 64) {
    // stage K [64][64] via global_load_lds, source pre-swizzled (row&7)<<4
#pragma unroll
    for (int rep = 0; rep < 2; rep++) {
      int idx = rep * 256 + tid;
      int row = idx >> 3;
      int sw = ((idx & 7) * 16) ^ ((row & 7) << 4);
      gload_lds16((const char*)Kb + ((size_t)(t0 + row) * 64) * 2 + sw,
                  (char*)k_lds + (size_t)idx * 16);
    }
    // stage V transposed [d][t], dual-XOR swizzle conflict-free both sides
#pragma unroll
    for (int rep = 0; rep < 2; rep++) {
      int idx = rep * 256 + tid;
      int tv = idx >> 3;
      int dv = (idx & 7) * 8;
      bf16x8 vv = *(const bf16x8*)&Vb[(size_t)(t0 + tv) * 64 + dv];
#pragma unroll
      for (int j = 0; j < 8; j++) {
        int d = dv + j;
        int key = ((d & 7) ^ ((d >> 3) & 7)) << 3;
        v_lds[d * 64 + (tv ^ key)] = vv[j];
      }
    }
    __syncthreads();

    // QK^T: per wave 16 q-rows x 64 t-cols
    f32x4 sc4[4];
#pragma unroll
    for (int j = 0; j < 4; j++) {
      f32x4 z = {};
#pragma unroll
      for (int ks = 0; ks < 2; ks++) {
        int row = j * 16 + rlo;
        int koff = (ks * 32 + g * 8) ^ ((row & 7) << 3);
        bf16x8 bk = *(const bf16x8*)&k_lds[row * 64 + koff];
        z = __builtin_amdgcn_mfma_f32_16x16x32_bf16(aq[ks], bk, z, 0, 0, 0);
      }
      sc4[j] = z;
    }

    // online softmax (scores already carry 0.125*log2e -> use exp2)
    float scl[4];
#pragma unroll
    for (int r = 0; r < 4; r++) {
      float pm = fmaxf(fmaxf(sc4[0][r], sc4[1][r]), fmaxf(sc4[2][r], sc4[3][r]));
#pragma unroll
      for (int d_ = 1; d_ < 16; d_ <<= 1) pm = fmaxf(pm, __shfl_xor(pm, d_));
      float mn = fmaxf(m_r[r], pm);
      scl[r] = __builtin_amdgcn_exp2f(m_r[r] - mn);
      float rs = 0.f;
#pragma unroll
      for (int j = 0; j < 4; j++) {
        float p = __builtin_amdgcn_exp2f(sc4[j][r] - mn);
        sc4[j][r] = p;
        rs += p;
      }
#pragma unroll
      for (int d_ = 1; d_ < 16; d_ <<= 1) rs += __shfl_xor(rs, d_);
      l_r[r] = l_r[r] * scl[r] + rs;
      m_r[r] = mn;
    }
#pragma unroll
    for (int j = 0; j < 4; j++)
#pragma unroll
      for (int r = 0; r < 4; r++) o[j][r] *= scl[r];

    // write P (bf16) to wave-private LDS slab, swizzled like K
#pragma unroll
    for (int r = 0; r < 4; r++) {
      int rr = g * 4 + r;
      int key = (rr & 7) << 3;
#pragma unroll
      for (int j = 0; j < 4; j++) {
        int col = j * 16 + rlo;
        p_lds[(w * 16 + rr) * 64 + (col ^ key)] = (bf16)sc4[j][r];
      }
    }

    // PV: o[q][d] += P[q][t] * V[t][d]
#pragma unroll
    for (int ks = 0; ks < 2; ks++) {
      int pkey = (rlo & 7) << 3;
      bf16x8 pa = *(const bf16x8*)&p_lds[(w * 16 + rlo) * 64 + ((ks * 32 + g * 8) ^ pkey)];
#pragma unroll
      for (int j = 0; j < 4; j++) {
        int d = j * 16 + rlo;
        int vkey = ((d & 7) ^ ((d >> 3) & 7)) << 3;
        bf16x8 bv = *(const bf16x8*)&v_lds[d * 64 + ((ks * 32 + g * 8) ^ vkey)];
        o[j] = __builtin_amdgcn_mfma_f32_16x16x32_bf16(pa, bv, o[j], 0, 0, 0);
      }
    }
    __syncthreads();
  }

  // finalize: ctx[b][s][h*64+hd] bf16
  int h = bh & 15, bb = bh >> 4;
#pragma unroll
  for (int r = 0; r < 4; r++) {
    float inv = 1.0f / l_r[r];
    int ss = q0 + w * 16 + g * 4 + r;
    size_t base = (((size_t)(bb * 2048 + ss)) << 10) + h * 64;
#pragma unroll
    for (int j = 0; j < 4; j++)
      ctx[base + j * 16 + rlo] = (bf16)(o[j][r] * inv);
  }
}

// ---------------------------------------------------------------------------
extern "C" void kernel_launch(void* const* d_in, const int* in_sizes, int n_in,
                              void* d_out, int out_size, void* d_ws, size_t ws_size,
                              hipStream_t stream) {
  const float* x  = (const float*)d_in[0];
  const float* Wq = (const float*)d_in[1];
  const float* bq = (const float*)d_in[2];
  const float* Wk = (const float*)d_in[3];
  const float* bk = (const float*)d_in[4];
  const float* Wv = (const float*)d_in[5];
  const float* bv = (const float*)d_in[6];
  const float* Wo = (const float*)d_in[7];
  const float* bo = (const float*)d_in[8];
  float* out = (float*)d_out;
  char* ws = (char*)d_ws;

  bf16* xb = (bf16*)(ws + XB_OFF);
  bf16* wt = (bf16*)(ws + WT_OFF);
  bf16* Qb = (bf16*)(ws + Q_OFF);
  bf16* Kb = (bf16*)(ws + K_OFF);
  bf16* Vb = (bf16*)(ws + V_OFF);
  bf16* cx = (bf16*)(ws + CTX_OFF);

  cvt_x<<<4096, 256, 0, stream>>>(x, xb);
  cvt_w<<<dim3(16, 16, 4), 256, 0, stream>>>(Wq, Wk, Wv, Wo, wt);
  gemm_bt<0><<<dim3(64, 24), 256, 0, stream>>>(xb, wt, bq, bk, bv,
                                               Qb, Kb, Vb, nullptr);
  attn<<<dim3(32, 64), 256, 0, stream>>>(Qb, Kb, Vb, cx);
  gemm_bt<1><<<dim3(64, 8), 256, 0, stream>>>(cx, wt + 3ull * 1024 * 1024, bo,
                                              nullptr, nullptr, nullptr,
                                              nullptr, nullptr, out);
}